// Round 2
// 194.141 us; speedup vs baseline: 1.0132x; 1.0132x over previous
//
#include <hip/hip_runtime.h>

// YOLO-v1 loss, N=4096, S=14, 30 ch/cell. ~176 MB in, 5 floats out.
// R6/R7: lane-per-cell one-shot. Previous staged-chunk structure (R5) was
// latency-bound: per-chunk full vmcnt drains left ~1 line/wave outstanding
// on average -> pinned at 2.1-2.55 TB/s effective with all pipes idle
// (VALUBusy 12.6%, HBM 17%, MFMA 0). New structure: each lane owns one
// cell; 7 independent unconditional loads (box ch0-9 as 5x float2, tbox
// float4, obj dword) issue at wave start; pred-cls (ch10-29) AND tcls
// load exec-masked under obj (15% density) -> lines for ~85% of the
// 64 MB pred-cls region never requested. No LDS staging, no manual
// waitcnt, no cross-lane ops except the final reduction. IOU pairing is
// lane-local (both boxes in one lane).
// R7: identical to R6 (bench infra failed, kernel never ran); launch_bounds
// min-waves relaxed 6->4 as the only defensive change.

#define CELLS   802816              // 4096 * 14 * 14
#define THREADS 512
#define NBLK    (CELLS / THREADS)   // 1568 blocks, exactly 1 cell/thread
#define L_COORD 5.0f
#define L_NOOBJ 0.5f

__global__ __launch_bounds__(THREADS, 4) void yolo_main(
    const float* __restrict__ pred,    // [CELLS][30]
    const float* __restrict__ tbox,    // [CELLS][4]
    const float* __restrict__ tcls,    // [CELLS][20]
    const int*   __restrict__ objmap,  // [CELLS]
    float4*      __restrict__ part)    // [NBLK]
{
    __shared__ float red[8][4];

    const int tid  = threadIdx.x;
    const int lane = tid & 63;
    const int wv   = tid >> 6;
    const int cell = blockIdx.x * THREADS + tid;

    // ---- unconditional loads: 7 independent VMEM ops, issued up front ----
    const float* pb = pred + (size_t)cell * 30;        // 120 B stride, 8B-aligned
    const float2 q0 = *(const float2*)(pb + 0);        // x1 y1
    const float2 q1 = *(const float2*)(pb + 2);        // w1 h1
    const float2 q2 = *(const float2*)(pb + 4);        // c1 x2
    const float2 q3 = *(const float2*)(pb + 6);        // y2 w2
    const float2 q4 = *(const float2*)(pb + 8);        // h2 c2
    const float4 tb = ((const float4*)tbox)[cell];     // 16B-aligned
    const int   obj = objmap[cell];

    float acc_reg = 0.f, acc_cont = 0.f, acc_noobj = 0.f, acc_cls = 0.f;

    if (!obj) {
        // conf1^2 + conf2^2, both lane-local
        acc_noobj = q2.x * q2.x + q4.y * q4.y;
    } else {
        // ---- gated loads: ~15% of lanes active -> HW fetches only their lines
        const float2 c0 = *(const float2*)(pb + 10);
        const float2 c1 = *(const float2*)(pb + 12);
        const float2 c2 = *(const float2*)(pb + 14);
        const float2 c3 = *(const float2*)(pb + 16);
        const float2 c4 = *(const float2*)(pb + 18);
        const float2 c5 = *(const float2*)(pb + 20);
        const float2 c6 = *(const float2*)(pb + 22);
        const float2 c7 = *(const float2*)(pb + 24);
        const float2 c8 = *(const float2*)(pb + 26);
        const float2 c9 = *(const float2*)(pb + 28);
        const float4* tc = (const float4*)tcls + (size_t)cell * 5;  // 80 B/cell, aligned
        const float4 t0 = tc[0];
        const float4 t1 = tc[1];
        const float4 t2 = tc[2];
        const float4 t3 = tc[3];
        const float4 t4 = tc[4];

        // ---- cls loss: 20 squared diffs, all lane-local ----
        float s, d;
        d = c0.x - t0.x; s  = d * d;
        d = c0.y - t0.y; s += d * d;
        d = c1.x - t0.z; s += d * d;
        d = c1.y - t0.w; s += d * d;
        d = c2.x - t1.x; s += d * d;
        d = c2.y - t1.y; s += d * d;
        d = c3.x - t1.z; s += d * d;
        d = c3.y - t1.w; s += d * d;
        d = c4.x - t2.x; s += d * d;
        d = c4.y - t2.y; s += d * d;
        d = c5.x - t2.z; s += d * d;
        d = c5.y - t2.w; s += d * d;
        d = c6.x - t3.x; s += d * d;
        d = c6.y - t3.y; s += d * d;
        d = c7.x - t3.z; s += d * d;
        d = c7.y - t3.w; s += d * d;
        d = c8.x - t4.x; s += d * d;
        d = c8.y - t4.y; s += d * d;
        d = c9.x - t4.z; s += d * d;
        d = c9.y - t4.w; s += d * d;
        acc_cls = s;

        // ---- IOU for both boxes, lane-local (no shuffle pairing) ----
        const float invS = 1.0f / 14.0f;
        const float txc = tb.x * invS, tyc = tb.y * invS;
        const float tx1 = txc - 0.5f * tb.z, ty1 = tyc - 0.5f * tb.w;
        const float tx2 = txc + 0.5f * tb.z, ty2 = tyc + 0.5f * tb.w;
        const float ta  = (tx2 - tx1) * (ty2 - ty1);

        // box1: x=q0.x y=q0.y w=q1.x h=q1.y conf=q2.x
        float ax1 = q0.x * invS - 0.5f * q1.x, ay1 = q0.y * invS - 0.5f * q1.y;
        float ax2 = q0.x * invS + 0.5f * q1.x, ay2 = q0.y * invS + 0.5f * q1.y;
        float a1  = (ax2 - ax1) * (ay2 - ay1);
        float iw  = fmaxf(fminf(ax2, tx2) - fmaxf(ax1, tx1), 0.f);
        float ih  = fmaxf(fminf(ay2, ty2) - fmaxf(ay1, ty1), 0.f);
        float in1 = iw * ih;
        float iou1 = in1 / (a1 + ta - in1);

        // box2: x=q2.y y=q3.x w=q3.y h=q4.x conf=q4.y
        float bx1 = q2.y * invS - 0.5f * q3.y, by1 = q3.x * invS - 0.5f * q4.x;
        float bx2 = q2.y * invS + 0.5f * q3.y, by2 = q3.x * invS + 0.5f * q4.x;
        float a2  = (bx2 - bx1) * (by2 - by1);
        float jw  = fmaxf(fminf(bx2, tx2) - fmaxf(bx1, tx1), 0.f);
        float jh  = fmaxf(fminf(by2, ty2) - fmaxf(by1, ty1), 0.f);
        float in2 = jw * jh;
        float iou2 = in2 / (a2 + ta - in2);

        // reference: take1 = iou1 > iou2
        const bool t1w = iou1 > iou2;
        const float bx = t1w ? q0.x : q2.y;
        const float by = t1w ? q0.y : q3.x;
        const float bw = t1w ? q1.x : q3.y;
        const float bh = t1w ? q1.y : q4.x;
        const float bc = t1w ? q2.x : q4.y;
        const float bi = t1w ? iou1 : iou2;

        const float dx = bx - tb.x, dy = by - tb.y;
        const float dw = sqrtf(bw) - sqrtf(tb.z);
        const float dh = sqrtf(bh) - sqrtf(tb.w);
        acc_reg  = dx * dx + dy * dy + dw * dw + dh * dh;
        const float dc = bc - bi;
        acc_cont = dc * dc;
    }

    // ---- reduction: wave shfl tree -> LDS -> block partial ----
    #pragma unroll
    for (int off = 32; off > 0; off >>= 1) {
        acc_reg   += __shfl_down(acc_reg,   off);
        acc_cont  += __shfl_down(acc_cont,  off);
        acc_noobj += __shfl_down(acc_noobj, off);
        acc_cls   += __shfl_down(acc_cls,   off);
    }
    if (lane == 0) {
        red[wv][0] = acc_reg;
        red[wv][1] = acc_cont;
        red[wv][2] = acc_noobj;
        red[wv][3] = acc_cls;
    }
    __syncthreads();
    if (tid == 0) {
        float4 p = make_float4(0.f, 0.f, 0.f, 0.f);
        #pragma unroll
        for (int w = 0; w < 8; ++w) {
            p.x += red[w][0];
            p.y += red[w][1];
            p.z += red[w][2];
            p.w += red[w][3];
        }
        part[blockIdx.x] = p;
    }
}

__global__ __launch_bounds__(1024) void yolo_reduce(
    const float4* __restrict__ part, float* __restrict__ out)
{
    __shared__ float red[16][4];
    float r = 0.f, c = 0.f, n = 0.f, cl = 0.f;
    for (int i = threadIdx.x; i < NBLK; i += 1024) {   // 2 iters (second partial)
        float4 p = part[i];
        r += p.x; c += p.y; n += p.z; cl += p.w;
    }
    #pragma unroll
    for (int off = 32; off > 0; off >>= 1) {
        r  += __shfl_down(r,  off);
        c  += __shfl_down(c,  off);
        n  += __shfl_down(n,  off);
        cl += __shfl_down(cl, off);
    }
    const int wave = threadIdx.x >> 6, lane = threadIdx.x & 63;
    if (lane == 0) {
        red[wave][0] = r; red[wave][1] = c; red[wave][2] = n; red[wave][3] = cl;
    }
    __syncthreads();
    if (threadIdx.x == 0) {
        float R = 0.f, C = 0.f, Nn = 0.f, Cl = 0.f;
        #pragma unroll
        for (int w = 0; w < 16; ++w) {
            R += red[w][0]; C += red[w][1]; Nn += red[w][2]; Cl += red[w][3];
        }
        const float invN = 1.0f / 4096.0f;
        float reg   = L_COORD * R  * invN;
        float cont  =           C  * invN;
        float noobj = L_NOOBJ * Nn * invN;
        float cls   =           Cl * invN;
        out[0] = reg + cont + noobj + cls;
        out[1] = reg;
        out[2] = cont;
        out[3] = noobj;
        out[4] = cls;
    }
}

extern "C" void kernel_launch(void* const* d_in, const int* in_sizes, int n_in,
                              void* d_out, int out_size, void* d_ws, size_t ws_size,
                              hipStream_t stream) {
    const float* pred   = (const float*)d_in[0];
    const float* tbox   = (const float*)d_in[1];
    const float* tcls   = (const float*)d_in[2];
    const int*   objmap = (const int*)  d_in[3];
    float4* part = (float4*)d_ws;      // NBLK * 16 B = 25 KB, every slot written
    float*  out  = (float*)d_out;

    yolo_main<<<NBLK, THREADS, 0, stream>>>(pred, tbox, tcls, objmap, part);
    yolo_reduce<<<1, 1024, 0, stream>>>(part, out);
}